// Round 2
// baseline (4817.945 us; speedup 1.0000x reference)
//
#include <hip/hip_runtime.h>
#include <stdint.h>

// GRU S=512, B=64, D=H=1024, L=2 — persistent cooperative pipeline, v4.
// 256 WGs = 4 tasks x 64 slices, 1 WG/CU:
//   task0: xlin0[t] = x[t] @ wih0^T + bih0
//   task1: layer-0 GRU step t
//   task2: xlin1[t] = out0[t] @ out0-w^T + bih1
//   task3: layer-1 GRU step t -> d_out
// v4 changes vs v3 (theory: exposed LLC latency of serialized A-load half 2
// + tail barrier in the critical recurrence):
//   * Two A-register banks av0/av1: half1 loads ISSUE right after half0's
//     vmcnt(0) (separate asm block, no internal wait); mfma(half0) overlaps
//     half1 flight; then vmcnt(0)+sched_barrier(0)+mfma(half1).
//   * Per-wave done flags (4 ints in one 64B line per slice). Producer wave
//     flags itself after its own drain — NO tail __syncthreads. Consumers
//     read the line with one dwordx4 and take min4.

#define SLEN 512
#define HB   65536
#define G3   3072
#define XLSLOT (64 * 64 * 48)   // floats per xlin ring slot: [slice][row64][gate3][col16]

typedef __attribute__((ext_vector_type(8))) short bf16x8;
typedef __attribute__((ext_vector_type(4))) float f32x4;
typedef __attribute__((ext_vector_type(8))) uint16_t u16x8;
typedef __attribute__((ext_vector_type(4))) int i32x4;

__device__ __forceinline__ uint16_t f32_to_bf16(float f) {
  uint32_t u = __float_as_uint(f);
  uint32_t r = u + 0x7FFFu + ((u >> 16) & 1u);
  return (uint16_t)(r >> 16);
}
__device__ __forceinline__ float sigmoid_fast(float x) { return 1.0f / (1.0f + __expf(-x)); }
__device__ __forceinline__ float tanh_fast(float x) { return 1.0f - 2.0f / (1.0f + __expf(2.0f * x)); }
__device__ __forceinline__ void async_cp16(const void* g, void* l) {
  __builtin_amdgcn_global_load_lds((const __attribute__((address_space(1))) void*)g,
                                   (__attribute__((address_space(3))) void*)l, 16, 0, 0);
}
__device__ __forceinline__ void st_u16_llc(uint16_t* p, uint16_t v) {
  __hip_atomic_store(p, v, __ATOMIC_RELAXED, __HIP_MEMORY_SCOPE_AGENT);
}
__device__ __forceinline__ void st_f32_llc(float* p, float v) {
  __hip_atomic_store(p, v, __ATOMIC_RELAXED, __HIP_MEMORY_SCOPE_AGENT);
}
__device__ __forceinline__ void drain_vmem() {
  asm volatile("s_waitcnt vmcnt(0)" ::: "memory");
}
__device__ __forceinline__ void st_flag(int* p, int v) {
  __hip_atomic_store(p, v, __ATOMIC_RELAXED, __HIP_MEMORY_SCOPE_AGENT);
}
__device__ __forceinline__ i32x4 ld_flag4(const int* p) {
  i32x4 r;
  asm volatile("global_load_dwordx4 %0, %1, off sc1\n\ts_waitcnt vmcnt(0)"
               : "=v"(r) : "v"(p) : "memory");
  return r;
}
__device__ __forceinline__ int min4(i32x4 v) {
  int a = v[0] < v[1] ? v[0] : v[1];
  int b = v[2] < v[3] ? v[2] : v[3];
  return a < b ? a : b;
}

// ---- prep kernels -----------------------------------------------------------

__global__ __launch_bounds__(256) void convert_x(const float* __restrict__ src,
                                                 uint16_t* __restrict__ dst) {
  size_t i = ((size_t)blockIdx.x * 256 + threadIdx.x) * 8;
  const float4* s = (const float4*)(src + i);
  float4 a = s[0], b = s[1];
  u16x8 v;
  v[0] = f32_to_bf16(a.x); v[1] = f32_to_bf16(a.y);
  v[2] = f32_to_bf16(a.z); v[3] = f32_to_bf16(a.w);
  v[4] = f32_to_bf16(b.x); v[5] = f32_to_bf16(b.y);
  v[6] = f32_to_bf16(b.z); v[7] = f32_to_bf16(b.w);
  *(u16x8*)(dst + i) = v;
}

// (3072x1024 f32, row-major) -> MFMA B-fragment order:
// chunk = (tile*32 + ks)*64 + lane, holding w[16*tile + (lane&15)][32ks + (lane>>4)*8 ..+7]
__global__ __launch_bounds__(256) void pack_w(const float* __restrict__ src,
                                              uint16_t* __restrict__ dst) {
  int tid = blockIdx.x * 256 + threadIdx.x;
  int tile = tid >> 11, rem = tid & 2047, ks = rem >> 6, lane = rem & 63;
  int row = tile * 16 + (lane & 15);
  int k0 = ks * 32 + (lane >> 4) * 8;
  const float* s = src + (size_t)row * 1024 + k0;
  u16x8 v;
#pragma unroll
  for (int j = 0; j < 8; ++j) v[j] = f32_to_bf16(s[j]);
  *(u16x8*)(dst + (size_t)tid * 8) = v;
}

__global__ __launch_bounds__(256) void init_state(const float* __restrict__ hx,
                                                  uint16_t* __restrict__ h0b,
                                                  uint16_t* __restrict__ h1b,
                                                  int* __restrict__ flags) {
  int i = blockIdx.x * 256 + threadIdx.x;   // 65536 threads
  h0b[i] = f32_to_bf16(hx[i]);
  h1b[i] = f32_to_bf16(hx[HB + i]);
  if (blockIdx.x < 16) flags[blockIdx.x * 256 + threadIdx.x] = 0;  // 4096 ints
}

// ---- parallel flag wait -----------------------------------------------------
// Wave 0 only. Each condition (active iff target > 0): min4(line at p) >= t.
// p is a per-lane line address: base+lane*16 for all-64 waits (lane L checks
// slice L), base+slice*16 uniform for pairwise waits (broadcast line).
// Flags are monotonic => a lane stops reloading once satisfied.
__device__ __forceinline__ void poll3(const int* pa, int ta,
                                      const int* pb, int tb,
                                      const int* pc, int tc) {
  const int BIG = 0x7fffffff;
  int va = (ta > 0) ? min4(ld_flag4(pa)) : BIG;
  int vb = (tb > 0) ? min4(ld_flag4(pb)) : BIG;
  int vc = (tc > 0) ? min4(ld_flag4(pc)) : BIG;
  int it = 0;
  while (!__all((va >= ta) & (vb >= tb) & (vc >= tc))) {
    __builtin_amdgcn_s_sleep(1);
    if (va < ta) va = min4(ld_flag4(pa));
    if (vb < tb) vb = min4(ld_flag4(pb));
    if (vc < tc) vc = min4(ld_flag4(pc));
    if (++it > (1 << 22)) break;   // safety valve vs hang
  }
}

// ---- device-scope (sc1) load batches ---------------------------------------

// 16 A-fragments, waits vmcnt(0) inside.
__device__ __forceinline__ void load_a16_sc1(const uint16_t* p, bf16x8* a) {
  asm volatile(
      "global_load_dwordx4 %0, %16, off sc1\n\t"
      "global_load_dwordx4 %1, %16, off offset:64 sc1\n\t"
      "global_load_dwordx4 %2, %16, off offset:128 sc1\n\t"
      "global_load_dwordx4 %3, %16, off offset:192 sc1\n\t"
      "global_load_dwordx4 %4, %16, off offset:256 sc1\n\t"
      "global_load_dwordx4 %5, %16, off offset:320 sc1\n\t"
      "global_load_dwordx4 %6, %16, off offset:384 sc1\n\t"
      "global_load_dwordx4 %7, %16, off offset:448 sc1\n\t"
      "global_load_dwordx4 %8, %16, off offset:512 sc1\n\t"
      "global_load_dwordx4 %9, %16, off offset:576 sc1\n\t"
      "global_load_dwordx4 %10, %16, off offset:640 sc1\n\t"
      "global_load_dwordx4 %11, %16, off offset:704 sc1\n\t"
      "global_load_dwordx4 %12, %16, off offset:768 sc1\n\t"
      "global_load_dwordx4 %13, %16, off offset:832 sc1\n\t"
      "global_load_dwordx4 %14, %16, off offset:896 sc1\n\t"
      "global_load_dwordx4 %15, %16, off offset:960 sc1\n\t"
      "s_waitcnt vmcnt(0)"
      : "=&v"(a[0]), "=&v"(a[1]), "=&v"(a[2]), "=&v"(a[3]),
        "=&v"(a[4]), "=&v"(a[5]), "=&v"(a[6]), "=&v"(a[7]),
        "=&v"(a[8]), "=&v"(a[9]), "=&v"(a[10]), "=&v"(a[11]),
        "=&v"(a[12]), "=&v"(a[13]), "=&v"(a[14]), "=&v"(a[15])
      : "v"(p)
      : "memory");
}

// 16 A-fragments, NO wait — caller must s_waitcnt vmcnt(0) before using a[].
__device__ __forceinline__ void issue_a16_sc1(const uint16_t* p, bf16x8* a) {
  asm volatile(
      "global_load_dwordx4 %0, %16, off sc1\n\t"
      "global_load_dwordx4 %1, %16, off offset:64 sc1\n\t"
      "global_load_dwordx4 %2, %16, off offset:128 sc1\n\t"
      "global_load_dwordx4 %3, %16, off offset:192 sc1\n\t"
      "global_load_dwordx4 %4, %16, off offset:256 sc1\n\t"
      "global_load_dwordx4 %5, %16, off offset:320 sc1\n\t"
      "global_load_dwordx4 %6, %16, off offset:384 sc1\n\t"
      "global_load_dwordx4 %7, %16, off offset:448 sc1\n\t"
      "global_load_dwordx4 %8, %16, off offset:512 sc1\n\t"
      "global_load_dwordx4 %9, %16, off offset:576 sc1\n\t"
      "global_load_dwordx4 %10, %16, off offset:640 sc1\n\t"
      "global_load_dwordx4 %11, %16, off offset:704 sc1\n\t"
      "global_load_dwordx4 %12, %16, off offset:768 sc1\n\t"
      "global_load_dwordx4 %13, %16, off offset:832 sc1\n\t"
      "global_load_dwordx4 %14, %16, off offset:896 sc1\n\t"
      "global_load_dwordx4 %15, %16, off offset:960 sc1"
      : "=&v"(a[0]), "=&v"(a[1]), "=&v"(a[2]), "=&v"(a[3]),
        "=&v"(a[4]), "=&v"(a[5]), "=&v"(a[6]), "=&v"(a[7]),
        "=&v"(a[8]), "=&v"(a[9]), "=&v"(a[10]), "=&v"(a[11]),
        "=&v"(a[12]), "=&v"(a[13]), "=&v"(a[14]), "=&v"(a[15])
      : "v"(p)
      : "memory");
}

// 16 A-fragments + 12 xlin floats (offsets rg*192 + g*64), one vmcnt(0).
__device__ __forceinline__ void load_a16_xl12_sc1(const uint16_t* p, const float* px,
                                                  bf16x8* a, float* x) {
  asm volatile(
      "global_load_dword %16, %29, off sc1\n\t"
      "global_load_dword %17, %29, off offset:64 sc1\n\t"
      "global_load_dword %18, %29, off offset:128 sc1\n\t"
      "global_load_dword %19, %29, off offset:192 sc1\n\t"
      "global_load_dword %20, %29, off offset:256 sc1\n\t"
      "global_load_dword %21, %29, off offset:320 sc1\n\t"
      "global_load_dword %22, %29, off offset:384 sc1\n\t"
      "global_load_dword %23, %29, off offset:448 sc1\n\t"
      "global_load_dword %24, %29, off offset:512 sc1\n\t"
      "global_load_dword %25, %29, off offset:576 sc1\n\t"
      "global_load_dword %26, %29, off offset:640 sc1\n\t"
      "global_load_dword %27, %29, off offset:704 sc1\n\t"
      "global_load_dwordx4 %0, %28, off sc1\n\t"
      "global_load_dwordx4 %1, %28, off offset:64 sc1\n\t"
      "global_load_dwordx4 %2, %28, off offset:128 sc1\n\t"
      "global_load_dwordx4 %3, %28, off offset:192 sc1\n\t"
      "global_load_dwordx4 %4, %28, off offset:256 sc1\n\t"
      "global_load_dwordx4 %5, %28, off offset:320 sc1\n\t"
      "global_load_dwordx4 %6, %28, off offset:384 sc1\n\t"
      "global_load_dwordx4 %7, %28, off offset:448 sc1\n\t"
      "global_load_dwordx4 %8, %28, off offset:512 sc1\n\t"
      "global_load_dwordx4 %9, %28, off offset:576 sc1\n\t"
      "global_load_dwordx4 %10, %28, off offset:640 sc1\n\t"
      "global_load_dwordx4 %11, %28, off offset:704 sc1\n\t"
      "global_load_dwordx4 %12, %28, off offset:768 sc1\n\t"
      "global_load_dwordx4 %13, %28, off offset:832 sc1\n\t"
      "global_load_dwordx4 %14, %28, off offset:896 sc1\n\t"
      "global_load_dwordx4 %15, %28, off offset:960 sc1\n\t"
      "s_waitcnt vmcnt(0)"
      : "=&v"(a[0]), "=&v"(a[1]), "=&v"(a[2]), "=&v"(a[3]),
        "=&v"(a[4]), "=&v"(a[5]), "=&v"(a[6]), "=&v"(a[7]),
        "=&v"(a[8]), "=&v"(a[9]), "=&v"(a[10]), "=&v"(a[11]),
        "=&v"(a[12]), "=&v"(a[13]), "=&v"(a[14]), "=&v"(a[15]),
        "=&v"(x[0]), "=&v"(x[1]), "=&v"(x[2]), "=&v"(x[3]),
        "=&v"(x[4]), "=&v"(x[5]), "=&v"(x[6]), "=&v"(x[7]),
        "=&v"(x[8]), "=&v"(x[9]), "=&v"(x[10]), "=&v"(x[11])
      : "v"(p), "v"(px)
      : "memory");
}

// ---- persistent kernel ------------------------------------------------------

// B fragments for 16 K-chunks starting at bbase; gate stride 16384 u16 (32 KB).
__device__ __forceinline__ void mfma16(const bf16x8* av, const uint16_t* bbase, int lane,
                                       f32x4& acc0, f32x4& acc1, f32x4& acc2) {
#pragma unroll
  for (int ks = 0; ks < 16; ++ks) {
    const uint16_t* bp = bbase + (size_t)(ks * 64 + lane) * 8;
    bf16x8 b0 = *(const bf16x8*)(bp);
    bf16x8 b1 = *(const bf16x8*)(bp + 16384);
    bf16x8 b2 = *(const bf16x8*)(bp + 32768);
    acc0 = __builtin_amdgcn_mfma_f32_16x16x32_bf16(av[ks], b0, acc0, 0, 0, 0);
    acc1 = __builtin_amdgcn_mfma_f32_16x16x32_bf16(av[ks], b1, acc1, 0, 0, 0);
    acc2 = __builtin_amdgcn_mfma_f32_16x16x32_bf16(av[ks], b2, acc2, 0, 0, 0);
  }
}

__global__ __launch_bounds__(256, 1) void gru_persist(
    const uint16_t* __restrict__ x_bf,
    const uint16_t* __restrict__ wih0, const uint16_t* __restrict__ whh0,
    const uint16_t* __restrict__ wih1, const uint16_t* __restrict__ whh1,
    const float* __restrict__ bih0, const float* __restrict__ bhh0,
    const float* __restrict__ bih1, const float* __restrict__ bhh1,
    const float* __restrict__ hx,
    float* __restrict__ xl0, float* __restrict__ xl1,
    uint16_t* __restrict__ o0r,
    uint16_t* __restrict__ h0b, uint16_t* __restrict__ h1b,
    int* __restrict__ flags,
    float* __restrict__ out) {
  // 96 KB: the WG's FULL B slice (3 gates x K=1024 x 16 cols), LDS-persistent.
  __shared__ uint16_t blds[49152];

  const int task = blockIdx.x >> 6;
  const int slice = blockIdx.x & 63;
  const int tid = threadIdx.x;
  const int lane = tid & 63;
  const int wv = tid >> 6;
  const int r15 = lane & 15;
  const int q = lane >> 4;
  const int c = slice * 16 + r15;           // output column
  const int m = 16 * wv + 4 * q;            // batch row base

  // per-wave store-only flags: doneT[slice] line = 4 ints (one per wave)
  int* done0 = flags;
  int* done1 = flags + 1024;
  int* done2 = flags + 2048;
  int* done3 = flags + 3072;
  int* mydone = (task == 0) ? done0 : (task == 1) ? done1 : (task == 2) ? done2 : done3;
  int* myflag = mydone + slice * 16 + wv;

  const uint16_t* Bw = (task == 0) ? wih0 : (task == 1) ? whh0 : (task == 2) ? wih1 : whh1;
  const float* bv = (task == 0) ? bih0 : (task == 1) ? bhh0 : (task == 2) ? bih1 : bhh1;
  const float br = bv[c], bz = bv[1024 + c], bn = bv[2048 + c];

  float hreg[4];
  if (task == 1 || task == 3) {
    const int layer = (task == 3);
#pragma unroll
    for (int rg = 0; rg < 4; ++rg)
      hreg[rg] = hx[(size_t)layer * HB + (size_t)(m + rg) * 1024 + c];
  }

  // ---- one-time weight stage: 6144 chunks of 16B -> blds (wave-linear dest)
#pragma unroll
  for (int i = 0; i < 24; ++i) {
    int s2 = i * 256 + tid;                 // (g, ks, l)
    int g = s2 >> 11, rem = s2 & 2047, ks = rem >> 6, l = rem & 63;
    const uint16_t* gp = Bw + (size_t)(g * 64 + slice) * 16384 +
                         (size_t)ks * 512 + l * 8;
    async_cp16(gp, blds + (size_t)s2 * 8);
  }
  drain_vmem();
  __syncthreads();                          // all waves' chunks resident

  for (int t = 0; t < SLEN; ++t) {
    // ---- single combined wait per step (wave 0 polls, others park) ----
    if (wv == 0) {
      if (task == 0) {
        poll3(done1 + slice * 16, t - 3,      // xl0 slot free (pairwise)
              flags, 0, flags, 0);
      } else if (task == 1) {
        poll3(done0 + slice * 16, t + 1,      // xlin0[t] slice ready (pairwise)
              done1 + lane * 16, t,           // h0[t] complete + ping-pong safe (all)
              done2 + lane * 16, t - 3);      // o0r ring slot free (all)
      } else if (task == 2) {
        poll3(done1 + lane * 16, t + 1,       // out0[t] complete (all)
              done3 + slice * 16, t - 3,      // xl1 slot free (pairwise)
              flags, 0);
      } else {
        poll3(done2 + slice * 16, t + 1,      // xlin1[t] slice ready (pairwise)
              done3 + lane * 16, t,           // h1[t] complete + ping-pong safe (all)
              flags, 0);
      }
    }
    __syncthreads();

    f32x4 acc0 = {0.f, 0.f, 0.f, 0.f}, acc1 = acc0, acc2 = acc0;
    bf16x8 av0[16], av1[16];
    float xv[12];

    if (task == 1 || task == 3) {
      const uint16_t* hb = (task == 1) ? h0b : h1b;
      const float* xlr = (task == 1) ? xl0 : xl1;
      const uint16_t* ap = hb + (size_t)(t & 1) * HB + (size_t)(16 * wv + r15) * 1024 + q * 8;
      const float* xlp = xlr + (size_t)(t & 3) * XLSLOT + (size_t)(slice * 64 + m) * 48 + r15;

      load_a16_xl12_sc1(ap, xlp, av0, xv);  // h half 0 + xlin, vmcnt(0) inside
      issue_a16_sc1(ap + 512, av1);         // h half 1 in flight under mfma(half0)
      mfma16(av0, blds, lane, acc0, acc1, acc2);
      asm volatile("s_waitcnt vmcnt(0)" ::: "memory");
      __builtin_amdgcn_sched_barrier(0);
      mfma16(av1, blds + 8192, lane, acc0, acc1, acc2);

      uint16_t* hbw = ((task == 1) ? h0b : h1b) + (size_t)((t + 1) & 1) * HB;
      uint16_t* orow = o0r + (size_t)(t & 3) * HB;
#pragma unroll
      for (int rg = 0; rg < 4; ++rg) {
        int mm = m + rg;
        float r = sigmoid_fast(xv[rg * 3 + 0] + acc0[rg] + br);
        float z = sigmoid_fast(xv[rg * 3 + 1] + acc1[rg] + bz);
        float n = tanh_fast(xv[rg * 3 + 2] + r * (acc2[rg] + bn));
        float h = (1.0f - z) * n + z * hreg[rg];
        hreg[rg] = h;
        uint16_t hb16 = f32_to_bf16(h);
        st_u16_llc(hbw + (size_t)mm * 1024 + c, hb16);     // sc1 write-through
        if (task == 1) st_u16_llc(orow + (size_t)mm * 1024 + c, hb16);
        else out[(size_t)t * HB + (size_t)mm * 1024 + c] = h;   // host-only: normal
      }
    } else {
      if (task == 0) {
        const uint16_t* ap = x_bf + (size_t)t * HB + (size_t)(16 * wv + r15) * 1024 + q * 8;
#pragma unroll
        for (int ks = 0; ks < 16; ++ks) av0[ks] = *(const bf16x8*)(ap + ks * 32);
#pragma unroll
        for (int ks = 0; ks < 16; ++ks) av1[ks] = *(const bf16x8*)(ap + 512 + ks * 32);
        mfma16(av0, blds, lane, acc0, acc1, acc2);
        mfma16(av1, blds + 8192, lane, acc0, acc1, acc2);
      } else {
        const uint16_t* ap = o0r + (size_t)(t & 3) * HB + (size_t)(16 * wv + r15) * 1024 + q * 8;
        load_a16_sc1(ap, av0);              // vmcnt(0) inside
        issue_a16_sc1(ap + 512, av1);       // half 1 in flight under mfma(half0)
        mfma16(av0, blds, lane, acc0, acc1, acc2);
        asm volatile("s_waitcnt vmcnt(0)" ::: "memory");
        __builtin_amdgcn_sched_barrier(0);
        mfma16(av1, blds + 8192, lane, acc0, acc1, acc2);
      }
      float* dst = ((task == 0) ? xl0 : xl1) + (size_t)(t & 3) * XLSLOT + (size_t)slice * 64 * 48;
#pragma unroll
      for (int rg = 0; rg < 4; ++rg) {
        int mm = m + rg;
        st_f32_llc(dst + (size_t)mm * 48 + r15,      acc0[rg] + br);
        st_f32_llc(dst + (size_t)mm * 48 + 16 + r15, acc1[rg] + bz);
        st_f32_llc(dst + (size_t)mm * 48 + 32 + r15, acc2[rg] + bn);
      }
    }

    drain_vmem();                           // this wave's stores at LLC
    st_flag(myflag, t + 1);                 // per-wave store-only signal
  }

  // final hidden state (L,B,H) appended after out sequence
  if (task == 1 || task == 3) {
    const int layer = (task == 3);
#pragma unroll
    for (int rg = 0; rg < 4; ++rg)
      out[(size_t)SLEN * HB + (size_t)layer * HB + (size_t)(m + rg) * 1024 + c] = hreg[rg];
  }
}

// ---- host -------------------------------------------------------------------

extern "C" void kernel_launch(void* const* d_in, const int* in_sizes, int n_in,
                              void* d_out, int out_size, void* d_ws, size_t ws_size,
                              hipStream_t stream) {
  (void)in_sizes; (void)n_in; (void)out_size; (void)ws_size;
  const float* x = (const float*)d_in[0];
  const float* hx = (const float*)d_in[1];
  const float* wih0f = (const float*)d_in[2];
  const float* whh0f = (const float*)d_in[3];
  const float* bih0 = (const float*)d_in[4];
  const float* bhh0 = (const float*)d_in[5];
  const float* wih1f = (const float*)d_in[6];
  const float* whh1f = (const float*)d_in[7];
  const float* bih1 = (const float*)d_in[8];
  const float* bhh1 = (const float*)d_in[9];
  float* out = (float*)d_out;

  char* ws = (char*)d_ws;
  uint16_t* x_bf = (uint16_t*)ws; ws += (size_t)SLEN * HB * 2;     // 64 MB
  uint16_t* wih0 = (uint16_t*)ws; ws += (size_t)G3 * 1024 * 2;     // 6 MB each
  uint16_t* whh0 = (uint16_t*)ws; ws += (size_t)G3 * 1024 * 2;
  uint16_t* wih1 = (uint16_t*)ws; ws += (size_t)G3 * 1024 * 2;
  uint16_t* whh1 = (uint16_t*)ws; ws += (size_t)G3 * 1024 * 2;
  float* xl0 = (float*)ws; ws += (size_t)4 * XLSLOT * 4;           // 3 MB ring
  float* xl1 = (float*)ws; ws += (size_t)4 * XLSLOT * 4;           // 3 MB ring
  uint16_t* o0r = (uint16_t*)ws; ws += (size_t)4 * HB * 2;         // 512 KB ring
  uint16_t* h0b = (uint16_t*)ws; ws += (size_t)2 * HB * 2;
  uint16_t* h1b = (uint16_t*)ws; ws += (size_t)2 * HB * 2;
  int* flags = (int*)ws; ws += 16384;                              // 4096 ints, 64B lines

  convert_x<<<16384, 256, 0, stream>>>(x, x_bf);
  pack_w<<<1536, 256, 0, stream>>>(wih0f, wih0);
  pack_w<<<1536, 256, 0, stream>>>(whh0f, whh0);
  pack_w<<<1536, 256, 0, stream>>>(wih1f, wih1);
  pack_w<<<1536, 256, 0, stream>>>(whh1f, whh1);
  init_state<<<256, 256, 0, stream>>>(hx, h0b, h1b, flags);

  const uint16_t* cx = x_bf;
  const uint16_t* cw0 = wih0; const uint16_t* cw1 = whh0;
  const uint16_t* cw2 = wih1; const uint16_t* cw3 = whh1;
  void* args[] = {(void*)&cx, (void*)&cw0, (void*)&cw1, (void*)&cw2, (void*)&cw3,
                  (void*)&bih0, (void*)&bhh0, (void*)&bih1, (void*)&bhh1, (void*)&hx,
                  (void*)&xl0, (void*)&xl1, (void*)&o0r, (void*)&h0b, (void*)&h1b,
                  (void*)&flags, (void*)&out};
  hipError_t e = hipLaunchCooperativeKernel(reinterpret_cast<void*>(gru_persist),
                                            dim3(256), dim3(256), args, 0u, stream);
  if (e != hipSuccess) {
    gru_persist<<<dim3(256), dim3(256), 0, stream>>>(
        x_bf, wih0, whh0, wih1, whh1, bih0, bhh0, bih1, bhh1, hx,
        xl0, xl1, o0r, h0b, h1b, flags, out);
  }
}

// Round 3
// 4681.034 us; speedup vs baseline: 1.0292x; 1.0292x over previous
//
#include <hip/hip_runtime.h>
#include <stdint.h>

// GRU S=512, B=64, D=H=1024, L=2 — persistent cooperative pipeline, v5.
// 256 WGs = 4 tasks x 64 slices, 1 WG/CU:
//   task0: xlin0[t] = x[t] @ wih0^T + bih0
//   task1: layer-0 GRU step t
//   task2: xlin1[t] = out0[t] @ wih1^T + bih1
//   task3: layer-1 GRU step t -> d_out
// v5 changes vs v4 (theory: consumer-side stale-L2 invalidation lag is the
// period; sc1 loads hit the local XCD L2 — FETCH_SIZE arithmetic proves it —
// so flags AND data only become visible when cross-XCD invalidations land):
//   * All inter-WG data loads + flag polls use system scope (sc0 sc1): read
//     the LLC (point of coherence) directly, no dependence on invalidation
//     propagation. Weights keep normal cached loads (L2-resident).
//   * task3's out[] HBM stores moved AFTER the flag store — HBM write acks
//     retire under the next step's poll instead of inside the drain.

#define SLEN 512
#define HB   65536
#define G3   3072
#define XLSLOT (64 * 64 * 48)   // floats per xlin ring slot: [slice][row64][gate3][col16]

typedef __attribute__((ext_vector_type(8))) short bf16x8;
typedef __attribute__((ext_vector_type(4))) float f32x4;
typedef __attribute__((ext_vector_type(8))) uint16_t u16x8;
typedef __attribute__((ext_vector_type(4))) int i32x4;

__device__ __forceinline__ uint16_t f32_to_bf16(float f) {
  uint32_t u = __float_as_uint(f);
  uint32_t r = u + 0x7FFFu + ((u >> 16) & 1u);
  return (uint16_t)(r >> 16);
}
__device__ __forceinline__ float sigmoid_fast(float x) { return 1.0f / (1.0f + __expf(-x)); }
__device__ __forceinline__ float tanh_fast(float x) { return 1.0f - 2.0f / (1.0f + __expf(2.0f * x)); }
__device__ __forceinline__ void async_cp16(const void* g, void* l) {
  __builtin_amdgcn_global_load_lds((const __attribute__((address_space(1))) void*)g,
                                   (__attribute__((address_space(3))) void*)l, 16, 0, 0);
}
__device__ __forceinline__ void st_u16_llc(uint16_t* p, uint16_t v) {
  __hip_atomic_store(p, v, __ATOMIC_RELAXED, __HIP_MEMORY_SCOPE_AGENT);
}
__device__ __forceinline__ void st_f32_llc(float* p, float v) {
  __hip_atomic_store(p, v, __ATOMIC_RELAXED, __HIP_MEMORY_SCOPE_AGENT);
}
__device__ __forceinline__ void drain_vmem() {
  asm volatile("s_waitcnt vmcnt(0)" ::: "memory");
}
__device__ __forceinline__ void st_flag(int* p, int v) {
  __hip_atomic_store(p, v, __ATOMIC_RELAXED, __HIP_MEMORY_SCOPE_AGENT);
}
// System-scope poll load: bypasses (stale) L2, reads LLC directly.
__device__ __forceinline__ i32x4 ld_flag4(const int* p) {
  i32x4 r;
  asm volatile("global_load_dwordx4 %0, %1, off sc0 sc1\n\ts_waitcnt vmcnt(0)"
               : "=v"(r) : "v"(p) : "memory");
  return r;
}
__device__ __forceinline__ int min4(i32x4 v) {
  int a = v[0] < v[1] ? v[0] : v[1];
  int b = v[2] < v[3] ? v[2] : v[3];
  return a < b ? a : b;
}

// ---- prep kernels -----------------------------------------------------------

__global__ __launch_bounds__(256) void convert_x(const float* __restrict__ src,
                                                 uint16_t* __restrict__ dst) {
  size_t i = ((size_t)blockIdx.x * 256 + threadIdx.x) * 8;
  const float4* s = (const float4*)(src + i);
  float4 a = s[0], b = s[1];
  u16x8 v;
  v[0] = f32_to_bf16(a.x); v[1] = f32_to_bf16(a.y);
  v[2] = f32_to_bf16(a.z); v[3] = f32_to_bf16(a.w);
  v[4] = f32_to_bf16(b.x); v[5] = f32_to_bf16(b.y);
  v[6] = f32_to_bf16(b.z); v[7] = f32_to_bf16(b.w);
  *(u16x8*)(dst + i) = v;
}

// (3072x1024 f32, row-major) -> MFMA B-fragment order:
// chunk = (tile*32 + ks)*64 + lane, holding w[16*tile + (lane&15)][32ks + (lane>>4)*8 ..+7]
__global__ __launch_bounds__(256) void pack_w(const float* __restrict__ src,
                                              uint16_t* __restrict__ dst) {
  int tid = blockIdx.x * 256 + threadIdx.x;
  int tile = tid >> 11, rem = tid & 2047, ks = rem >> 6, lane = rem & 63;
  int row = tile * 16 + (lane & 15);
  int k0 = ks * 32 + (lane >> 4) * 8;
  const float* s = src + (size_t)row * 1024 + k0;
  u16x8 v;
#pragma unroll
  for (int j = 0; j < 8; ++j) v[j] = f32_to_bf16(s[j]);
  *(u16x8*)(dst + (size_t)tid * 8) = v;
}

__global__ __launch_bounds__(256) void init_state(const float* __restrict__ hx,
                                                  uint16_t* __restrict__ h0b,
                                                  uint16_t* __restrict__ h1b,
                                                  int* __restrict__ flags) {
  int i = blockIdx.x * 256 + threadIdx.x;   // 65536 threads
  h0b[i] = f32_to_bf16(hx[i]);
  h1b[i] = f32_to_bf16(hx[HB + i]);
  if (blockIdx.x < 16) flags[blockIdx.x * 256 + threadIdx.x] = 0;  // 4096 ints
}

// ---- parallel flag wait -----------------------------------------------------
// Wave 0 only. Each condition (active iff target > 0): min4(line at p) >= t.
// p is a per-lane line address: base+lane*16 for all-64 waits (lane L checks
// slice L), base+slice*16 uniform for pairwise waits (broadcast line).
// Flags are monotonic => a lane stops reloading once satisfied.
__device__ __forceinline__ void poll3(const int* pa, int ta,
                                      const int* pb, int tb,
                                      const int* pc, int tc) {
  const int BIG = 0x7fffffff;
  int va = (ta > 0) ? min4(ld_flag4(pa)) : BIG;
  int vb = (tb > 0) ? min4(ld_flag4(pb)) : BIG;
  int vc = (tc > 0) ? min4(ld_flag4(pc)) : BIG;
  int it = 0;
  while (!__all((va >= ta) & (vb >= tb) & (vc >= tc))) {
    __builtin_amdgcn_s_sleep(1);
    if (va < ta) va = min4(ld_flag4(pa));
    if (vb < tb) vb = min4(ld_flag4(pb));
    if (vc < tc) vc = min4(ld_flag4(pc));
    if (++it > (1 << 22)) break;   // safety valve vs hang
  }
}

// ---- system-scope (sc0 sc1) load batches -----------------------------------

// 16 A-fragments, waits vmcnt(0) inside.
__device__ __forceinline__ void load_a16_sc1(const uint16_t* p, bf16x8* a) {
  asm volatile(
      "global_load_dwordx4 %0, %16, off sc0 sc1\n\t"
      "global_load_dwordx4 %1, %16, off offset:64 sc0 sc1\n\t"
      "global_load_dwordx4 %2, %16, off offset:128 sc0 sc1\n\t"
      "global_load_dwordx4 %3, %16, off offset:192 sc0 sc1\n\t"
      "global_load_dwordx4 %4, %16, off offset:256 sc0 sc1\n\t"
      "global_load_dwordx4 %5, %16, off offset:320 sc0 sc1\n\t"
      "global_load_dwordx4 %6, %16, off offset:384 sc0 sc1\n\t"
      "global_load_dwordx4 %7, %16, off offset:448 sc0 sc1\n\t"
      "global_load_dwordx4 %8, %16, off offset:512 sc0 sc1\n\t"
      "global_load_dwordx4 %9, %16, off offset:576 sc0 sc1\n\t"
      "global_load_dwordx4 %10, %16, off offset:640 sc0 sc1\n\t"
      "global_load_dwordx4 %11, %16, off offset:704 sc0 sc1\n\t"
      "global_load_dwordx4 %12, %16, off offset:768 sc0 sc1\n\t"
      "global_load_dwordx4 %13, %16, off offset:832 sc0 sc1\n\t"
      "global_load_dwordx4 %14, %16, off offset:896 sc0 sc1\n\t"
      "global_load_dwordx4 %15, %16, off offset:960 sc0 sc1\n\t"
      "s_waitcnt vmcnt(0)"
      : "=&v"(a[0]), "=&v"(a[1]), "=&v"(a[2]), "=&v"(a[3]),
        "=&v"(a[4]), "=&v"(a[5]), "=&v"(a[6]), "=&v"(a[7]),
        "=&v"(a[8]), "=&v"(a[9]), "=&v"(a[10]), "=&v"(a[11]),
        "=&v"(a[12]), "=&v"(a[13]), "=&v"(a[14]), "=&v"(a[15])
      : "v"(p)
      : "memory");
}

// 16 A-fragments, NO wait — caller must s_waitcnt vmcnt(0) before using a[].
__device__ __forceinline__ void issue_a16_sc1(const uint16_t* p, bf16x8* a) {
  asm volatile(
      "global_load_dwordx4 %0, %16, off sc0 sc1\n\t"
      "global_load_dwordx4 %1, %16, off offset:64 sc0 sc1\n\t"
      "global_load_dwordx4 %2, %16, off offset:128 sc0 sc1\n\t"
      "global_load_dwordx4 %3, %16, off offset:192 sc0 sc1\n\t"
      "global_load_dwordx4 %4, %16, off offset:256 sc0 sc1\n\t"
      "global_load_dwordx4 %5, %16, off offset:320 sc0 sc1\n\t"
      "global_load_dwordx4 %6, %16, off offset:384 sc0 sc1\n\t"
      "global_load_dwordx4 %7, %16, off offset:448 sc0 sc1\n\t"
      "global_load_dwordx4 %8, %16, off offset:512 sc0 sc1\n\t"
      "global_load_dwordx4 %9, %16, off offset:576 sc0 sc1\n\t"
      "global_load_dwordx4 %10, %16, off offset:640 sc0 sc1\n\t"
      "global_load_dwordx4 %11, %16, off offset:704 sc0 sc1\n\t"
      "global_load_dwordx4 %12, %16, off offset:768 sc0 sc1\n\t"
      "global_load_dwordx4 %13, %16, off offset:832 sc0 sc1\n\t"
      "global_load_dwordx4 %14, %16, off offset:896 sc0 sc1\n\t"
      "global_load_dwordx4 %15, %16, off offset:960 sc0 sc1"
      : "=&v"(a[0]), "=&v"(a[1]), "=&v"(a[2]), "=&v"(a[3]),
        "=&v"(a[4]), "=&v"(a[5]), "=&v"(a[6]), "=&v"(a[7]),
        "=&v"(a[8]), "=&v"(a[9]), "=&v"(a[10]), "=&v"(a[11]),
        "=&v"(a[12]), "=&v"(a[13]), "=&v"(a[14]), "=&v"(a[15])
      : "v"(p)
      : "memory");
}

// 16 A-fragments + 12 xlin floats (offsets rg*192 + g*64), one vmcnt(0).
__device__ __forceinline__ void load_a16_xl12_sc1(const uint16_t* p, const float* px,
                                                  bf16x8* a, float* x) {
  asm volatile(
      "global_load_dword %16, %29, off sc0 sc1\n\t"
      "global_load_dword %17, %29, off offset:64 sc0 sc1\n\t"
      "global_load_dword %18, %29, off offset:128 sc0 sc1\n\t"
      "global_load_dword %19, %29, off offset:192 sc0 sc1\n\t"
      "global_load_dword %20, %29, off offset:256 sc0 sc1\n\t"
      "global_load_dword %21, %29, off offset:320 sc0 sc1\n\t"
      "global_load_dword %22, %29, off offset:384 sc0 sc1\n\t"
      "global_load_dword %23, %29, off offset:448 sc0 sc1\n\t"
      "global_load_dword %24, %29, off offset:512 sc0 sc1\n\t"
      "global_load_dword %25, %29, off offset:576 sc0 sc1\n\t"
      "global_load_dword %26, %29, off offset:640 sc0 sc1\n\t"
      "global_load_dword %27, %29, off offset:704 sc0 sc1\n\t"
      "global_load_dwordx4 %0, %28, off sc0 sc1\n\t"
      "global_load_dwordx4 %1, %28, off offset:64 sc0 sc1\n\t"
      "global_load_dwordx4 %2, %28, off offset:128 sc0 sc1\n\t"
      "global_load_dwordx4 %3, %28, off offset:192 sc0 sc1\n\t"
      "global_load_dwordx4 %4, %28, off offset:256 sc0 sc1\n\t"
      "global_load_dwordx4 %5, %28, off offset:320 sc0 sc1\n\t"
      "global_load_dwordx4 %6, %28, off offset:384 sc0 sc1\n\t"
      "global_load_dwordx4 %7, %28, off offset:448 sc0 sc1\n\t"
      "global_load_dwordx4 %8, %28, off offset:512 sc0 sc1\n\t"
      "global_load_dwordx4 %9, %28, off offset:576 sc0 sc1\n\t"
      "global_load_dwordx4 %10, %28, off offset:640 sc0 sc1\n\t"
      "global_load_dwordx4 %11, %28, off offset:704 sc0 sc1\n\t"
      "global_load_dwordx4 %12, %28, off offset:768 sc0 sc1\n\t"
      "global_load_dwordx4 %13, %28, off offset:832 sc0 sc1\n\t"
      "global_load_dwordx4 %14, %28, off offset:896 sc0 sc1\n\t"
      "global_load_dwordx4 %15, %28, off offset:960 sc0 sc1\n\t"
      "s_waitcnt vmcnt(0)"
      : "=&v"(a[0]), "=&v"(a[1]), "=&v"(a[2]), "=&v"(a[3]),
        "=&v"(a[4]), "=&v"(a[5]), "=&v"(a[6]), "=&v"(a[7]),
        "=&v"(a[8]), "=&v"(a[9]), "=&v"(a[10]), "=&v"(a[11]),
        "=&v"(a[12]), "=&v"(a[13]), "=&v"(a[14]), "=&v"(a[15]),
        "=&v"(x[0]), "=&v"(x[1]), "=&v"(x[2]), "=&v"(x[3]),
        "=&v"(x[4]), "=&v"(x[5]), "=&v"(x[6]), "=&v"(x[7]),
        "=&v"(x[8]), "=&v"(x[9]), "=&v"(x[10]), "=&v"(x[11])
      : "v"(p), "v"(px)
      : "memory");
}

// ---- persistent kernel ------------------------------------------------------

// B fragments for 16 K-chunks starting at bbase; gate stride 16384 u16 (32 KB).
__device__ __forceinline__ void mfma16(const bf16x8* av, const uint16_t* bbase, int lane,
                                       f32x4& acc0, f32x4& acc1, f32x4& acc2) {
#pragma unroll
  for (int ks = 0; ks < 16; ++ks) {
    const uint16_t* bp = bbase + (size_t)(ks * 64 + lane) * 8;
    bf16x8 b0 = *(const bf16x8*)(bp);
    bf16x8 b1 = *(const bf16x8*)(bp + 16384);
    bf16x8 b2 = *(const bf16x8*)(bp + 32768);
    acc0 = __builtin_amdgcn_mfma_f32_16x16x32_bf16(av[ks], b0, acc0, 0, 0, 0);
    acc1 = __builtin_amdgcn_mfma_f32_16x16x32_bf16(av[ks], b1, acc1, 0, 0, 0);
    acc2 = __builtin_amdgcn_mfma_f32_16x16x32_bf16(av[ks], b2, acc2, 0, 0, 0);
  }
}

__global__ __launch_bounds__(256, 1) void gru_persist(
    const uint16_t* __restrict__ x_bf,
    const uint16_t* __restrict__ wih0, const uint16_t* __restrict__ whh0,
    const uint16_t* __restrict__ wih1, const uint16_t* __restrict__ whh1,
    const float* __restrict__ bih0, const float* __restrict__ bhh0,
    const float* __restrict__ bih1, const float* __restrict__ bhh1,
    const float* __restrict__ hx,
    float* __restrict__ xl0, float* __restrict__ xl1,
    uint16_t* __restrict__ o0r,
    uint16_t* __restrict__ h0b, uint16_t* __restrict__ h1b,
    int* __restrict__ flags,
    float* __restrict__ out) {
  // 96 KB: the WG's FULL B slice (3 gates x K=1024 x 16 cols), LDS-persistent.
  __shared__ uint16_t blds[49152];

  const int task = blockIdx.x >> 6;
  const int slice = blockIdx.x & 63;
  const int tid = threadIdx.x;
  const int lane = tid & 63;
  const int wv = tid >> 6;
  const int r15 = lane & 15;
  const int q = lane >> 4;
  const int c = slice * 16 + r15;           // output column
  const int m = 16 * wv + 4 * q;            // batch row base

  // per-wave store-only flags: doneT[slice] line = 4 ints (one per wave)
  int* done0 = flags;
  int* done1 = flags + 1024;
  int* done2 = flags + 2048;
  int* done3 = flags + 3072;
  int* mydone = (task == 0) ? done0 : (task == 1) ? done1 : (task == 2) ? done2 : done3;
  int* myflag = mydone + slice * 16 + wv;

  const uint16_t* Bw = (task == 0) ? wih0 : (task == 1) ? whh0 : (task == 2) ? wih1 : whh1;
  const float* bv = (task == 0) ? bih0 : (task == 1) ? bhh0 : (task == 2) ? bih1 : bhh1;
  const float br = bv[c], bz = bv[1024 + c], bn = bv[2048 + c];

  float hreg[4];
  if (task == 1 || task == 3) {
    const int layer = (task == 3);
#pragma unroll
    for (int rg = 0; rg < 4; ++rg)
      hreg[rg] = hx[(size_t)layer * HB + (size_t)(m + rg) * 1024 + c];
  }

  // ---- one-time weight stage: 6144 chunks of 16B -> blds (wave-linear dest)
#pragma unroll
  for (int i = 0; i < 24; ++i) {
    int s2 = i * 256 + tid;                 // (g, ks, l)
    int g = s2 >> 11, rem = s2 & 2047, ks = rem >> 6, l = rem & 63;
    const uint16_t* gp = Bw + (size_t)(g * 64 + slice) * 16384 +
                         (size_t)ks * 512 + l * 8;
    async_cp16(gp, blds + (size_t)s2 * 8);
  }
  drain_vmem();
  __syncthreads();                          // all waves' chunks resident

  for (int t = 0; t < SLEN; ++t) {
    // ---- single combined wait per step (wave 0 polls, others park) ----
    if (wv == 0) {
      if (task == 0) {
        poll3(done1 + slice * 16, t - 3,      // xl0 slot free (pairwise)
              flags, 0, flags, 0);
      } else if (task == 1) {
        poll3(done0 + slice * 16, t + 1,      // xlin0[t] slice ready (pairwise)
              done1 + lane * 16, t,           // h0[t] complete + ping-pong safe (all)
              done2 + lane * 16, t - 3);      // o0r ring slot free (all)
      } else if (task == 2) {
        poll3(done1 + lane * 16, t + 1,       // out0[t] complete (all)
              done3 + slice * 16, t - 3,      // xl1 slot free (pairwise)
              flags, 0);
      } else {
        poll3(done2 + slice * 16, t + 1,      // xlin1[t] slice ready (pairwise)
              done3 + lane * 16, t,           // h1[t] complete + ping-pong safe (all)
              flags, 0);
      }
    }
    __syncthreads();

    f32x4 acc0 = {0.f, 0.f, 0.f, 0.f}, acc1 = acc0, acc2 = acc0;
    bf16x8 av0[16], av1[16];
    float xv[12];

    if (task == 1 || task == 3) {
      const uint16_t* hb = (task == 1) ? h0b : h1b;
      const float* xlr = (task == 1) ? xl0 : xl1;
      const uint16_t* ap = hb + (size_t)(t & 1) * HB + (size_t)(16 * wv + r15) * 1024 + q * 8;
      const float* xlp = xlr + (size_t)(t & 3) * XLSLOT + (size_t)(slice * 64 + m) * 48 + r15;

      load_a16_xl12_sc1(ap, xlp, av0, xv);  // h half 0 + xlin, vmcnt(0) inside
      issue_a16_sc1(ap + 512, av1);         // h half 1 in flight under mfma(half0)
      mfma16(av0, blds, lane, acc0, acc1, acc2);
      asm volatile("s_waitcnt vmcnt(0)" ::: "memory");
      __builtin_amdgcn_sched_barrier(0);
      mfma16(av1, blds + 8192, lane, acc0, acc1, acc2);

      uint16_t* hbw = ((task == 1) ? h0b : h1b) + (size_t)((t + 1) & 1) * HB;
      uint16_t* orow = o0r + (size_t)(t & 3) * HB;
#pragma unroll
      for (int rg = 0; rg < 4; ++rg) {
        int mm = m + rg;
        float r = sigmoid_fast(xv[rg * 3 + 0] + acc0[rg] + br);
        float z = sigmoid_fast(xv[rg * 3 + 1] + acc1[rg] + bz);
        float n = tanh_fast(xv[rg * 3 + 2] + r * (acc2[rg] + bn));
        float h = (1.0f - z) * n + z * hreg[rg];
        hreg[rg] = h;
        uint16_t hb16 = f32_to_bf16(h);
        st_u16_llc(hbw + (size_t)mm * 1024 + c, hb16);     // sc1 write-through
        if (task == 1) st_u16_llc(orow + (size_t)mm * 1024 + c, hb16);
      }
      drain_vmem();                         // h (+o0r) stores at LLC
      st_flag(myflag, t + 1);               // per-wave store-only signal
      if (task == 3) {
        // host-only out[] stores AFTER the flag: HBM acks retire under the
        // next step's poll instead of inside the recurrence-critical drain.
#pragma unroll
        for (int rg = 0; rg < 4; ++rg)
          out[(size_t)t * HB + (size_t)(m + rg) * 1024 + c] = hreg[rg];
      }
    } else {
      if (task == 0) {
        const uint16_t* ap = x_bf + (size_t)t * HB + (size_t)(16 * wv + r15) * 1024 + q * 8;
#pragma unroll
        for (int ks = 0; ks < 16; ++ks) av0[ks] = *(const bf16x8*)(ap + ks * 32);
#pragma unroll
        for (int ks = 0; ks < 16; ++ks) av1[ks] = *(const bf16x8*)(ap + 512 + ks * 32);
        mfma16(av0, blds, lane, acc0, acc1, acc2);
        mfma16(av1, blds + 8192, lane, acc0, acc1, acc2);
      } else {
        const uint16_t* ap = o0r + (size_t)(t & 3) * HB + (size_t)(16 * wv + r15) * 1024 + q * 8;
        load_a16_sc1(ap, av0);              // vmcnt(0) inside
        issue_a16_sc1(ap + 512, av1);       // half 1 in flight under mfma(half0)
        mfma16(av0, blds, lane, acc0, acc1, acc2);
        asm volatile("s_waitcnt vmcnt(0)" ::: "memory");
        __builtin_amdgcn_sched_barrier(0);
        mfma16(av1, blds + 8192, lane, acc0, acc1, acc2);
      }
      float* dst = ((task == 0) ? xl0 : xl1) + (size_t)(t & 3) * XLSLOT + (size_t)slice * 64 * 48;
#pragma unroll
      for (int rg = 0; rg < 4; ++rg) {
        int mm = m + rg;
        st_f32_llc(dst + (size_t)mm * 48 + r15,      acc0[rg] + br);
        st_f32_llc(dst + (size_t)mm * 48 + 16 + r15, acc1[rg] + bz);
        st_f32_llc(dst + (size_t)mm * 48 + 32 + r15, acc2[rg] + bn);
      }
      drain_vmem();                         // this wave's stores at LLC
      st_flag(myflag, t + 1);               // per-wave store-only signal
    }
  }

  // final hidden state (L,B,H) appended after out sequence
  if (task == 1 || task == 3) {
    const int layer = (task == 3);
#pragma unroll
    for (int rg = 0; rg < 4; ++rg)
      out[(size_t)SLEN * HB + (size_t)layer * HB + (size_t)(m + rg) * 1024 + c] = hreg[rg];
  }
}

// ---- host -------------------------------------------------------------------

extern "C" void kernel_launch(void* const* d_in, const int* in_sizes, int n_in,
                              void* d_out, int out_size, void* d_ws, size_t ws_size,
                              hipStream_t stream) {
  (void)in_sizes; (void)n_in; (void)out_size; (void)ws_size;
  const float* x = (const float*)d_in[0];
  const float* hx = (const float*)d_in[1];
  const float* wih0f = (const float*)d_in[2];
  const float* whh0f = (const float*)d_in[3];
  const float* bih0 = (const float*)d_in[4];
  const float* bhh0 = (const float*)d_in[5];
  const float* wih1f = (const float*)d_in[6];
  const float* whh1f = (const float*)d_in[7];
  const float* bih1 = (const float*)d_in[8];
  const float* bhh1 = (const float*)d_in[9];
  float* out = (float*)d_out;

  char* ws = (char*)d_ws;
  uint16_t* x_bf = (uint16_t*)ws; ws += (size_t)SLEN * HB * 2;     // 64 MB
  uint16_t* wih0 = (uint16_t*)ws; ws += (size_t)G3 * 1024 * 2;     // 6 MB each
  uint16_t* whh0 = (uint16_t*)ws; ws += (size_t)G3 * 1024 * 2;
  uint16_t* wih1 = (uint16_t*)ws; ws += (size_t)G3 * 1024 * 2;
  uint16_t* whh1 = (uint16_t*)ws; ws += (size_t)G3 * 1024 * 2;
  float* xl0 = (float*)ws; ws += (size_t)4 * XLSLOT * 4;           // 3 MB ring
  float* xl1 = (float*)ws; ws += (size_t)4 * XLSLOT * 4;           // 3 MB ring
  uint16_t* o0r = (uint16_t*)ws; ws += (size_t)4 * HB * 2;         // 512 KB ring
  uint16_t* h0b = (uint16_t*)ws; ws += (size_t)2 * HB * 2;
  uint16_t* h1b = (uint16_t*)ws; ws += (size_t)2 * HB * 2;
  int* flags = (int*)ws; ws += 16384;                              // 4096 ints, 64B lines

  convert_x<<<16384, 256, 0, stream>>>(x, x_bf);
  pack_w<<<1536, 256, 0, stream>>>(wih0f, wih0);
  pack_w<<<1536, 256, 0, stream>>>(whh0f, whh0);
  pack_w<<<1536, 256, 0, stream>>>(wih1f, wih1);
  pack_w<<<1536, 256, 0, stream>>>(whh1f, whh1);
  init_state<<<256, 256, 0, stream>>>(hx, h0b, h1b, flags);

  const uint16_t* cx = x_bf;
  const uint16_t* cw0 = wih0; const uint16_t* cw1 = whh0;
  const uint16_t* cw2 = wih1; const uint16_t* cw3 = whh1;
  void* args[] = {(void*)&cx, (void*)&cw0, (void*)&cw1, (void*)&cw2, (void*)&cw3,
                  (void*)&bih0, (void*)&bhh0, (void*)&bih1, (void*)&bhh1, (void*)&hx,
                  (void*)&xl0, (void*)&xl1, (void*)&o0r, (void*)&h0b, (void*)&h1b,
                  (void*)&flags, (void*)&out};
  hipError_t e = hipLaunchCooperativeKernel(reinterpret_cast<void*>(gru_persist),
                                            dim3(256), dim3(256), args, 0u, stream);
  if (e != hipSuccess) {
    gru_persist<<<dim3(256), dim3(256), 0, stream>>>(
        x_bf, wih0, whh0, wih1, whh1, bih0, bhh0, bih1, bhh1, hx,
        xl0, xl1, o0r, h0b, h1b, flags, out);
  }
}

// Round 4
// 4468.407 us; speedup vs baseline: 1.0782x; 1.0476x over previous
//
#include <hip/hip_runtime.h>
#include <stdint.h>

// GRU S=512, B=64, D=H=1024, L=2 — persistent cooperative pipeline, v6.
// 256 WGs = 4 tasks x 64 slices, 1 WG/CU:
//   task0: xlin0[t] = x[t] @ wih0^T + bih0
//   task1: layer-0 GRU step t
//   task2: xlin1[t] = out0[t] @ wih1^T + bih1
//   task3: layer-1 GRU step t -> d_out
// v6 = v3 sync mechanics (best measured: 4262us) + split-K wait + deep rings.
//   * SPLIT-K WAIT: A K-half 0 (cols 0..511) is produced by slices 0..31 only.
//     Pre-step poll waits for lanes 0..31 (+ pairwise/ring conds); half-1's
//     producers (slices 32..63) are polled AFTER mfma(half0) — straggler
//     detection overlaps compute instead of serializing ahead of it.
//   * Rings deepened to 8 slots: ring-free checks (t-7) pre-satisfied in
//     steady state; task0 runs ahead so task1's wait is pure recurrence.
//   * Reverted v4/v5 regressions: serial half-loads with internal vmcnt(0),
//     single-int per-slice flags stored by tid0 after tail barrier, sc1 only.
//   * Kept from v5: task3's out[] HBM stores after the flag (off drain path).

#define SLEN 512
#define HB   65536
#define G3   3072
#define XLSLOT (64 * 64 * 48)   // floats per xlin ring slot: [slice][row64][gate3][col16]

typedef __attribute__((ext_vector_type(8))) short bf16x8;
typedef __attribute__((ext_vector_type(4))) float f32x4;
typedef __attribute__((ext_vector_type(8))) uint16_t u16x8;

__device__ __forceinline__ uint16_t f32_to_bf16(float f) {
  uint32_t u = __float_as_uint(f);
  uint32_t r = u + 0x7FFFu + ((u >> 16) & 1u);
  return (uint16_t)(r >> 16);
}
__device__ __forceinline__ float sigmoid_fast(float x) { return 1.0f / (1.0f + __expf(-x)); }
__device__ __forceinline__ float tanh_fast(float x) { return 1.0f - 2.0f / (1.0f + __expf(2.0f * x)); }
__device__ __forceinline__ void async_cp16(const void* g, void* l) {
  __builtin_amdgcn_global_load_lds((const __attribute__((address_space(1))) void*)g,
                                   (__attribute__((address_space(3))) void*)l, 16, 0, 0);
}
__device__ __forceinline__ void st_u16_llc(uint16_t* p, uint16_t v) {
  __hip_atomic_store(p, v, __ATOMIC_RELAXED, __HIP_MEMORY_SCOPE_AGENT);
}
__device__ __forceinline__ void st_f32_llc(float* p, float v) {
  __hip_atomic_store(p, v, __ATOMIC_RELAXED, __HIP_MEMORY_SCOPE_AGENT);
}
__device__ __forceinline__ void drain_vmem() {
  asm volatile("s_waitcnt vmcnt(0)" ::: "memory");
}
__device__ __forceinline__ int ld_flag(const int* p) {
  return __hip_atomic_load(p, __ATOMIC_RELAXED, __HIP_MEMORY_SCOPE_AGENT);
}
__device__ __forceinline__ void st_flag(int* p, int v) {
  __hip_atomic_store(p, v, __ATOMIC_RELAXED, __HIP_MEMORY_SCOPE_AGENT);
}

// ---- prep kernels -----------------------------------------------------------

__global__ __launch_bounds__(256) void convert_x(const float* __restrict__ src,
                                                 uint16_t* __restrict__ dst) {
  size_t i = ((size_t)blockIdx.x * 256 + threadIdx.x) * 8;
  const float4* s = (const float4*)(src + i);
  float4 a = s[0], b = s[1];
  u16x8 v;
  v[0] = f32_to_bf16(a.x); v[1] = f32_to_bf16(a.y);
  v[2] = f32_to_bf16(a.z); v[3] = f32_to_bf16(a.w);
  v[4] = f32_to_bf16(b.x); v[5] = f32_to_bf16(b.y);
  v[6] = f32_to_bf16(b.z); v[7] = f32_to_bf16(b.w);
  *(u16x8*)(dst + i) = v;
}

// (3072x1024 f32, row-major) -> MFMA B-fragment order:
// chunk = (tile*32 + ks)*64 + lane, holding w[16*tile + (lane&15)][32ks + (lane>>4)*8 ..+7]
__global__ __launch_bounds__(256) void pack_w(const float* __restrict__ src,
                                              uint16_t* __restrict__ dst) {
  int tid = blockIdx.x * 256 + threadIdx.x;
  int tile = tid >> 11, rem = tid & 2047, ks = rem >> 6, lane = rem & 63;
  int row = tile * 16 + (lane & 15);
  int k0 = ks * 32 + (lane >> 4) * 8;
  const float* s = src + (size_t)row * 1024 + k0;
  u16x8 v;
#pragma unroll
  for (int j = 0; j < 8; ++j) v[j] = f32_to_bf16(s[j]);
  *(u16x8*)(dst + (size_t)tid * 8) = v;
}

__global__ __launch_bounds__(256) void init_state(const float* __restrict__ hx,
                                                  uint16_t* __restrict__ h0b,
                                                  uint16_t* __restrict__ h1b,
                                                  int* __restrict__ flags) {
  int i = blockIdx.x * 256 + threadIdx.x;   // 65536 threads
  h0b[i] = f32_to_bf16(hx[i]);
  h1b[i] = f32_to_bf16(hx[HB + i]);
  if (blockIdx.x < 16) flags[blockIdx.x * 256 + threadIdx.x] = 0;  // 4096 ints
}

// ---- parallel flag wait -----------------------------------------------------
// Wave 0 only. Up to 3 conditions, each per-lane: value at aK >= tK.
// A lane passes tK <= 0 to disable its condition. Flags monotonic => a lane
// stops reloading once satisfied.
__device__ __forceinline__ void pollA(const int* a0, int t0,
                                      const int* a1, int t1,
                                      const int* a2, int t2) {
  const int BIG = 0x7fffffff;
  int v0 = (t0 > 0) ? ld_flag(a0) : BIG;
  int v1 = (t1 > 0) ? ld_flag(a1) : BIG;
  int v2 = (t2 > 0) ? ld_flag(a2) : BIG;
  int it = 0;
  while (!__all((v0 >= t0) & (v1 >= t1) & (v2 >= t2))) {
    __builtin_amdgcn_s_sleep(1);
    if (v0 < t0) v0 = ld_flag(a0);
    if (v1 < t1) v1 = ld_flag(a1);
    if (v2 < t2) v2 = ld_flag(a2);
    if (++it > (1 << 22)) break;   // safety valve vs hang
  }
}

// ---- device-scope (sc1) load batches ---------------------------------------

// 16 A-fragments, waits vmcnt(0) inside.
__device__ __forceinline__ void load_a16_sc1(const uint16_t* p, bf16x8* a) {
  asm volatile(
      "global_load_dwordx4 %0, %16, off sc1\n\t"
      "global_load_dwordx4 %1, %16, off offset:64 sc1\n\t"
      "global_load_dwordx4 %2, %16, off offset:128 sc1\n\t"
      "global_load_dwordx4 %3, %16, off offset:192 sc1\n\t"
      "global_load_dwordx4 %4, %16, off offset:256 sc1\n\t"
      "global_load_dwordx4 %5, %16, off offset:320 sc1\n\t"
      "global_load_dwordx4 %6, %16, off offset:384 sc1\n\t"
      "global_load_dwordx4 %7, %16, off offset:448 sc1\n\t"
      "global_load_dwordx4 %8, %16, off offset:512 sc1\n\t"
      "global_load_dwordx4 %9, %16, off offset:576 sc1\n\t"
      "global_load_dwordx4 %10, %16, off offset:640 sc1\n\t"
      "global_load_dwordx4 %11, %16, off offset:704 sc1\n\t"
      "global_load_dwordx4 %12, %16, off offset:768 sc1\n\t"
      "global_load_dwordx4 %13, %16, off offset:832 sc1\n\t"
      "global_load_dwordx4 %14, %16, off offset:896 sc1\n\t"
      "global_load_dwordx4 %15, %16, off offset:960 sc1\n\t"
      "s_waitcnt vmcnt(0)"
      : "=&v"(a[0]), "=&v"(a[1]), "=&v"(a[2]), "=&v"(a[3]),
        "=&v"(a[4]), "=&v"(a[5]), "=&v"(a[6]), "=&v"(a[7]),
        "=&v"(a[8]), "=&v"(a[9]), "=&v"(a[10]), "=&v"(a[11]),
        "=&v"(a[12]), "=&v"(a[13]), "=&v"(a[14]), "=&v"(a[15])
      : "v"(p)
      : "memory");
}

// 16 A-fragments + 12 xlin floats (offsets rg*192 + g*64), one vmcnt(0).
__device__ __forceinline__ void load_a16_xl12_sc1(const uint16_t* p, const float* px,
                                                  bf16x8* a, float* x) {
  asm volatile(
      "global_load_dword %16, %29, off sc1\n\t"
      "global_load_dword %17, %29, off offset:64 sc1\n\t"
      "global_load_dword %18, %29, off offset:128 sc1\n\t"
      "global_load_dword %19, %29, off offset:192 sc1\n\t"
      "global_load_dword %20, %29, off offset:256 sc1\n\t"
      "global_load_dword %21, %29, off offset:320 sc1\n\t"
      "global_load_dword %22, %29, off offset:384 sc1\n\t"
      "global_load_dword %23, %29, off offset:448 sc1\n\t"
      "global_load_dword %24, %29, off offset:512 sc1\n\t"
      "global_load_dword %25, %29, off offset:576 sc1\n\t"
      "global_load_dword %26, %29, off offset:640 sc1\n\t"
      "global_load_dword %27, %29, off offset:704 sc1\n\t"
      "global_load_dwordx4 %0, %28, off sc1\n\t"
      "global_load_dwordx4 %1, %28, off offset:64 sc1\n\t"
      "global_load_dwordx4 %2, %28, off offset:128 sc1\n\t"
      "global_load_dwordx4 %3, %28, off offset:192 sc1\n\t"
      "global_load_dwordx4 %4, %28, off offset:256 sc1\n\t"
      "global_load_dwordx4 %5, %28, off offset:320 sc1\n\t"
      "global_load_dwordx4 %6, %28, off offset:384 sc1\n\t"
      "global_load_dwordx4 %7, %28, off offset:448 sc1\n\t"
      "global_load_dwordx4 %8, %28, off offset:512 sc1\n\t"
      "global_load_dwordx4 %9, %28, off offset:576 sc1\n\t"
      "global_load_dwordx4 %10, %28, off offset:640 sc1\n\t"
      "global_load_dwordx4 %11, %28, off offset:704 sc1\n\t"
      "global_load_dwordx4 %12, %28, off offset:768 sc1\n\t"
      "global_load_dwordx4 %13, %28, off offset:832 sc1\n\t"
      "global_load_dwordx4 %14, %28, off offset:896 sc1\n\t"
      "global_load_dwordx4 %15, %28, off offset:960 sc1\n\t"
      "s_waitcnt vmcnt(0)"
      : "=&v"(a[0]), "=&v"(a[1]), "=&v"(a[2]), "=&v"(a[3]),
        "=&v"(a[4]), "=&v"(a[5]), "=&v"(a[6]), "=&v"(a[7]),
        "=&v"(a[8]), "=&v"(a[9]), "=&v"(a[10]), "=&v"(a[11]),
        "=&v"(a[12]), "=&v"(a[13]), "=&v"(a[14]), "=&v"(a[15]),
        "=&v"(x[0]), "=&v"(x[1]), "=&v"(x[2]), "=&v"(x[3]),
        "=&v"(x[4]), "=&v"(x[5]), "=&v"(x[6]), "=&v"(x[7]),
        "=&v"(x[8]), "=&v"(x[9]), "=&v"(x[10]), "=&v"(x[11])
      : "v"(p), "v"(px)
      : "memory");
}

// ---- persistent kernel ------------------------------------------------------

// B fragments for 16 K-chunks starting at bbase; gate stride 16384 u16 (32 KB).
__device__ __forceinline__ void mfma16(const bf16x8* av, const uint16_t* bbase, int lane,
                                       f32x4& acc0, f32x4& acc1, f32x4& acc2) {
#pragma unroll
  for (int ks = 0; ks < 16; ++ks) {
    const uint16_t* bp = bbase + (size_t)(ks * 64 + lane) * 8;
    bf16x8 b0 = *(const bf16x8*)(bp);
    bf16x8 b1 = *(const bf16x8*)(bp + 16384);
    bf16x8 b2 = *(const bf16x8*)(bp + 32768);
    acc0 = __builtin_amdgcn_mfma_f32_16x16x32_bf16(av[ks], b0, acc0, 0, 0, 0);
    acc1 = __builtin_amdgcn_mfma_f32_16x16x32_bf16(av[ks], b1, acc1, 0, 0, 0);
    acc2 = __builtin_amdgcn_mfma_f32_16x16x32_bf16(av[ks], b2, acc2, 0, 0, 0);
  }
}

__global__ __launch_bounds__(256, 1) void gru_persist(
    const uint16_t* __restrict__ x_bf,
    const uint16_t* __restrict__ wih0, const uint16_t* __restrict__ whh0,
    const uint16_t* __restrict__ wih1, const uint16_t* __restrict__ whh1,
    const float* __restrict__ bih0, const float* __restrict__ bhh0,
    const float* __restrict__ bih1, const float* __restrict__ bhh1,
    const float* __restrict__ hx,
    float* __restrict__ xl0, float* __restrict__ xl1,
    uint16_t* __restrict__ o0r,
    uint16_t* __restrict__ h0b, uint16_t* __restrict__ h1b,
    int* __restrict__ flags,
    float* __restrict__ out) {
  // 96 KB: the WG's FULL B slice (3 gates x K=1024 x 16 cols), LDS-persistent.
  __shared__ uint16_t blds[49152];

  const int task = blockIdx.x >> 6;
  const int slice = blockIdx.x & 63;
  const int tid = threadIdx.x;
  const int lane = tid & 63;
  const int wv = tid >> 6;
  const int r15 = lane & 15;
  const int q = lane >> 4;
  const int c = slice * 16 + r15;           // output column
  const int m = 16 * wv + 4 * q;            // batch row base

  // single-int store-only flags, one 64B line per slice: doneT[slice*16]
  int* done0 = flags;
  int* done1 = flags + 1024;
  int* done2 = flags + 2048;
  int* done3 = flags + 3072;
  int* mydone = (task == 0) ? done0 : (task == 1) ? done1 : (task == 2) ? done2 : done3;

  const uint16_t* Bw = (task == 0) ? wih0 : (task == 1) ? whh0 : (task == 2) ? wih1 : whh1;
  const float* bv = (task == 0) ? bih0 : (task == 1) ? bhh0 : (task == 2) ? bih1 : bhh1;
  const float br = bv[c], bz = bv[1024 + c], bn = bv[2048 + c];

  float hreg[4];
  if (task == 1 || task == 3) {
    const int layer = (task == 3);
#pragma unroll
    for (int rg = 0; rg < 4; ++rg)
      hreg[rg] = hx[(size_t)layer * HB + (size_t)(m + rg) * 1024 + c];
  }

  // ---- one-time weight stage: 6144 chunks of 16B -> blds (wave-linear dest)
#pragma unroll
  for (int i = 0; i < 24; ++i) {
    int s2 = i * 256 + tid;                 // (g, ks, l)
    int g = s2 >> 11, rem = s2 & 2047, ks = rem >> 6, l = rem & 63;
    const uint16_t* gp = Bw + (size_t)(g * 64 + slice) * 16384 +
                         (size_t)ks * 512 + l * 8;
    async_cp16(gp, blds + (size_t)s2 * 8);
  }
  drain_vmem();
  __syncthreads();                          // all waves' chunks resident

  // per-lane poll addresses (wave 0 uses these; lane L watches slice L)
  const int* pw_d1 = done1 + lane * 16;
  const int* pw_d2 = done2 + lane * 16;
  const int* pw_d3 = done3 + lane * 16;
  const int* sl_d0 = done0 + slice * 16;
  const int* sl_d1 = done1 + slice * 16;
  const int* sl_d2 = done2 + slice * 16;
  const int* sl_d3 = done3 + slice * 16;
  const int lo = (lane < 32);               // this lane watches a K-half-0 slice

  for (int t = 0; t < SLEN; ++t) {
    // ---- pre-step wait: K-half-0 producers + pairwise/ring conditions ----
    if (wv == 0) {
      if (task == 0) {
        pollA(sl_d1, t - 7, flags, 0, flags, 0);          // xl0 ring free (pairwise)
      } else if (task == 1) {
        pollA(sl_d0, t + 1,                               // xlin0[t] slice ready
              pw_d1, lo ? t : 0,                          // h0[t] half-0 written
              pw_d2, t - 7);                              // o0r ring slot free
      } else if (task == 2) {
        pollA(sl_d3, t - 7,                               // xl1 ring free (pairwise)
              pw_d1, lo ? t + 1 : 0,                      // out0[t] half-0 written
              flags, 0);
      } else {
        pollA(sl_d2, t + 1,                               // xlin1[t] slice ready
              pw_d3, lo ? t : 0,                          // h1[t] half-0 written
              flags, 0);
      }
    }
    __syncthreads();

    f32x4 acc0 = {0.f, 0.f, 0.f, 0.f}, acc1 = acc0, acc2 = acc0;
    bf16x8 av[16];
    float xv[12];

    if (task == 1 || task == 3) {
      const uint16_t* hb = (task == 1) ? h0b : h1b;
      const float* xlr = (task == 1) ? xl0 : xl1;
      const uint16_t* ap = hb + (size_t)(t & 1) * HB + (size_t)(16 * wv + r15) * 1024 + q * 8;
      const float* xlp = xlr + (size_t)(t & 7) * XLSLOT + (size_t)(slice * 64 + m) * 48 + r15;

      load_a16_xl12_sc1(ap, xlp, av, xv);   // h half 0 + xlin, vmcnt(0) inside
      mfma16(av, blds, lane, acc0, acc1, acc2);

      // straggler poll for K-half-1 producers OVERLAPPED behind mfma(half0)
      if (wv == 0) pollA(pw_d1 + ((task == 3) ? 2048 : 0), lo ? 0 : t, flags, 0, flags, 0);
      __syncthreads();

      load_a16_sc1(ap + 512, av);           // h half 1
      mfma16(av, blds + 8192, lane, acc0, acc1, acc2);

      uint16_t* hbw = ((task == 1) ? h0b : h1b) + (size_t)((t + 1) & 1) * HB;
      uint16_t* orow = o0r + (size_t)(t & 7) * HB;
#pragma unroll
      for (int rg = 0; rg < 4; ++rg) {
        int mm = m + rg;
        float r = sigmoid_fast(xv[rg * 3 + 0] + acc0[rg] + br);
        float z = sigmoid_fast(xv[rg * 3 + 1] + acc1[rg] + bz);
        float n = tanh_fast(xv[rg * 3 + 2] + r * (acc2[rg] + bn));
        float h = (1.0f - z) * n + z * hreg[rg];
        hreg[rg] = h;
        uint16_t hb16 = f32_to_bf16(h);
        st_u16_llc(hbw + (size_t)mm * 1024 + c, hb16);     // sc1 write-through
        if (task == 1) st_u16_llc(orow + (size_t)mm * 1024 + c, hb16);
      }
      drain_vmem();                         // this wave's stores at LLC
      __syncthreads();                      // => ALL waves' stores at LLC
      if (tid == 0) st_flag(mydone + slice * 16, t + 1);
      if (task == 3) {
        // host-only out[] stores AFTER the flag: off the recurrence drain path
#pragma unroll
        for (int rg = 0; rg < 4; ++rg)
          out[(size_t)t * HB + (size_t)(m + rg) * 1024 + c] = hreg[rg];
      }
    } else {
      if (task == 0) {
        const uint16_t* ap = x_bf + (size_t)t * HB + (size_t)(16 * wv + r15) * 1024 + q * 8;
#pragma unroll
        for (int ks = 0; ks < 16; ++ks) av[ks] = *(const bf16x8*)(ap + ks * 32);
        mfma16(av, blds, lane, acc0, acc1, acc2);
#pragma unroll
        for (int ks = 0; ks < 16; ++ks) av[ks] = *(const bf16x8*)(ap + 512 + ks * 32);
        mfma16(av, blds + 8192, lane, acc0, acc1, acc2);
      } else {
        const uint16_t* ap = o0r + (size_t)(t & 7) * HB + (size_t)(16 * wv + r15) * 1024 + q * 8;
        load_a16_sc1(ap, av);               // out0 half 0, vmcnt(0) inside
        mfma16(av, blds, lane, acc0, acc1, acc2);

        // straggler poll for out0 K-half-1 producers behind mfma(half0)
        if (wv == 0) pollA(pw_d1, lo ? 0 : t + 1, flags, 0, flags, 0);
        __syncthreads();

        load_a16_sc1(ap + 512, av);         // out0 half 1
        mfma16(av, blds + 8192, lane, acc0, acc1, acc2);
      }
      float* dst = ((task == 0) ? xl0 : xl1) + (size_t)(t & 7) * XLSLOT + (size_t)slice * 64 * 48;
#pragma unroll
      for (int rg = 0; rg < 4; ++rg) {
        int mm = m + rg;
        st_f32_llc(dst + (size_t)mm * 48 + r15,      acc0[rg] + br);
        st_f32_llc(dst + (size_t)mm * 48 + 16 + r15, acc1[rg] + bz);
        st_f32_llc(dst + (size_t)mm * 48 + 32 + r15, acc2[rg] + bn);
      }
      drain_vmem();
      __syncthreads();
      if (tid == 0) st_flag(mydone + slice * 16, t + 1);
    }
  }

  // final hidden state (L,B,H) appended after out sequence
  if (task == 1 || task == 3) {
    const int layer = (task == 3);
#pragma unroll
    for (int rg = 0; rg < 4; ++rg)
      out[(size_t)SLEN * HB + (size_t)layer * HB + (size_t)(m + rg) * 1024 + c] = hreg[rg];
  }
}

// ---- host -------------------------------------------------------------------

extern "C" void kernel_launch(void* const* d_in, const int* in_sizes, int n_in,
                              void* d_out, int out_size, void* d_ws, size_t ws_size,
                              hipStream_t stream) {
  (void)in_sizes; (void)n_in; (void)out_size; (void)ws_size;
  const float* x = (const float*)d_in[0];
  const float* hx = (const float*)d_in[1];
  const float* wih0f = (const float*)d_in[2];
  const float* whh0f = (const float*)d_in[3];
  const float* bih0 = (const float*)d_in[4];
  const float* bhh0 = (const float*)d_in[5];
  const float* wih1f = (const float*)d_in[6];
  const float* whh1f = (const float*)d_in[7];
  const float* bih1 = (const float*)d_in[8];
  const float* bhh1 = (const float*)d_in[9];
  float* out = (float*)d_out;

  char* ws = (char*)d_ws;
  uint16_t* x_bf = (uint16_t*)ws; ws += (size_t)SLEN * HB * 2;     // 64 MB
  uint16_t* wih0 = (uint16_t*)ws; ws += (size_t)G3 * 1024 * 2;     // 6 MB each
  uint16_t* whh0 = (uint16_t*)ws; ws += (size_t)G3 * 1024 * 2;
  uint16_t* wih1 = (uint16_t*)ws; ws += (size_t)G3 * 1024 * 2;
  uint16_t* whh1 = (uint16_t*)ws; ws += (size_t)G3 * 1024 * 2;
  float* xl0 = (float*)ws; ws += (size_t)8 * XLSLOT * 4;           // 6.3 MB ring (8 slots)
  float* xl1 = (float*)ws; ws += (size_t)8 * XLSLOT * 4;           // 6.3 MB ring
  uint16_t* o0r = (uint16_t*)ws; ws += (size_t)8 * HB * 2;         // 1 MB ring
  uint16_t* h0b = (uint16_t*)ws; ws += (size_t)2 * HB * 2;
  uint16_t* h1b = (uint16_t*)ws; ws += (size_t)2 * HB * 2;
  int* flags = (int*)ws; ws += 16384;                              // 4096 ints, 64B lines

  convert_x<<<16384, 256, 0, stream>>>(x, x_bf);
  pack_w<<<1536, 256, 0, stream>>>(wih0f, wih0);
  pack_w<<<1536, 256, 0, stream>>>(whh0f, whh0);
  pack_w<<<1536, 256, 0, stream>>>(wih1f, wih1);
  pack_w<<<1536, 256, 0, stream>>>(whh1f, whh1);
  init_state<<<256, 256, 0, stream>>>(hx, h0b, h1b, flags);

  const uint16_t* cx = x_bf;
  const uint16_t* cw0 = wih0; const uint16_t* cw1 = whh0;
  const uint16_t* cw2 = wih1; const uint16_t* cw3 = whh1;
  void* args[] = {(void*)&cx, (void*)&cw0, (void*)&cw1, (void*)&cw2, (void*)&cw3,
                  (void*)&bih0, (void*)&bhh0, (void*)&bih1, (void*)&bhh1, (void*)&hx,
                  (void*)&xl0, (void*)&xl1, (void*)&o0r, (void*)&h0b, (void*)&h1b,
                  (void*)&flags, (void*)&out};
  hipError_t e = hipLaunchCooperativeKernel(reinterpret_cast<void*>(gru_persist),
                                            dim3(256), dim3(256), args, 0u, stream);
  if (e != hipSuccess) {
    gru_persist<<<dim3(256), dim3(256), 0, stream>>>(
        x_bf, wih0, whh0, wih1, whh1, bih0, bhh0, bih1, bhh1, hx,
        xl0, xl1, o0r, h0b, h1b, flags, out);
  }
}